// Round 1
// baseline (1280.588 us; speedup 1.0000x reference)
//
#include <hip/hip_runtime.h>

#define DEVI __device__ __forceinline__

typedef __attribute__((ext_vector_type(8))) __bf16 bf16x8;
typedef __attribute__((ext_vector_type(4))) float f32x4;
typedef unsigned short u16;
typedef unsigned int u32;

static constexpr int kB = 32;
static constexpr int kL = 3137;           // 56*56+1
static constexpr int kM = kB * kL;        // 100384 rows total
static constexpr int kHeads = 12;
static constexpr float kScale = 0.17677669529663687f;  // 32^-0.5

DEVI u16 f2b(float f) {                   // f32 -> bf16 RNE
  u32 u = __float_as_uint(f);
  u32 r = (u + 0x7fffu + ((u >> 16) & 1u)) >> 16;
  return (u16)r;
}
DEVI float blo(u32 u) { return __uint_as_float(u << 16); }
DEVI float bhi(u32 u) { return __uint_as_float(u & 0xffff0000u); }
DEVI float b2f(u16 h) { return __uint_as_float(((u32)h) << 16); }

DEVI void async16(const void* g, void* l) {
  __builtin_amdgcn_global_load_lds((const __attribute__((address_space(1))) u32*)g,
                                   (__attribute__((address_space(3))) u32*)l, 16, 0, 0);
}

DEVI float wred_max(float v) {
#pragma unroll
  for (int o = 32; o; o >>= 1) v = fmaxf(v, __shfl_xor(v, o));
  return v;
}
DEVI float wred_sum(float v) {
#pragma unroll
  for (int o = 32; o; o >>= 1) v += __shfl_xor(v, o);
  return v;
}

// ---------------- weight f32 -> bf16 ----------------
__global__ void cvt_bf16(const float* __restrict__ in, u16* __restrict__ out, int n) {
  int i = blockIdx.x * 256 + threadIdx.x;
  if (i < n) out[i] = f2b(in[i]);
}

// ---------------- LayerNorm over 384, one wave per row, bf16 out ----------------
__global__ __launch_bounds__(64)
void ln384(const float* __restrict__ x, const float* __restrict__ g,
           const float* __restrict__ b, u16* __restrict__ out, int rows) {
  int row = blockIdx.x;
  if (row >= rows) return;
  const float* xr = x + (size_t)row * 384;
  int t = threadIdx.x;
  float v[6], s = 0.f, s2 = 0.f;
#pragma unroll
  for (int i = 0; i < 6; i++) {
    v[i] = xr[t + 64 * i];
    s += v[i];
    s2 += v[i] * v[i];
  }
  s = wred_sum(s);
  s2 = wred_sum(s2);
  float mean = s * (1.f / 384.f);
  float var = s2 * (1.f / 384.f) - mean * mean;
  float rinv = rsqrtf(var + 1e-5f);
  u16* orow = out + (size_t)row * 384;
#pragma unroll
  for (int i = 0; i < 6; i++) {
    int c = t + 64 * i;
    orow[c] = f2b((v[i] - mean) * rinv * g[c] + b[c]);
  }
}

DEVI float gelu_exact(float v) { return 0.5f * v * (1.f + erff(v * 0.70710678118654752f)); }

// ---------------- bf16 MFMA GEMM:  out = A(MxK) @ W(NxK)^T + bias [+res] ----------------
// 128x128 tile, BK=32, 4 waves (2x2), each wave 4x4 frags of 16x16x32.
// EPI: 0 = bias -> bf16 ; 1 = bias + res -> f32 ; 2 = bias + gelu -> bf16
template <int EPI>
__global__ __launch_bounds__(256)
void gemm_bt(const u16* __restrict__ A, const u16* __restrict__ W,
             const float* __restrict__ bias, const float* __restrict__ res,
             void* __restrict__ outp, int M, int N, int K) {
  const int tid = threadIdx.x, lane = tid & 63, wv = tid >> 6;
  const int col0 = blockIdx.x * 128, row0 = blockIdx.y * 128;
  __shared__ __align__(16) u16 As[2][128 * 32];
  __shared__ __align__(16) u16 Bs[2][128 * 32];
  f32x4 acc[4][4];
  f32x4 zero = {0.f, 0.f, 0.f, 0.f};
#pragma unroll
  for (int m = 0; m < 4; m++)
#pragma unroll
    for (int n = 0; n < 4; n++) acc[m][n] = zero;
  const int wm = wv >> 1, wn = wv & 1;
  const int NT = K >> 5;

  auto stage = [&](int kt, int bfi) {
#pragma unroll
    for (int s = 0; s < 2; s++) {
      int ch = wv * 2 + s;                     // 8 chunks of 16 rows x 64B
      int r = ch * 16 + (lane >> 2);
      int kk = kt * 32 + (lane & 3) * 8;
      const u16* gp = A + (size_t)min(row0 + r, M - 1) * K + kk;
      async16(gp, &As[bfi][ch * 512]);         // wave-uniform LDS base + lane*16B
      const u16* gq = W + (size_t)min(col0 + r, N - 1) * K + kk;
      async16(gq, &Bs[bfi][ch * 512]);
    }
  };

  stage(0, 0);
  __syncthreads();
  int bfi = 0;
  for (int kt = 0; kt < NT; ++kt) {
    if (kt + 1 < NT) stage(kt + 1, bfi ^ 1);
    bf16x8 af[4], bw[4];
#pragma unroll
    for (int m = 0; m < 4; m++)
      af[m] = *(const bf16x8*)&As[bfi][(wm * 64 + m * 16 + (lane & 15)) * 32 + (lane >> 4) * 8];
#pragma unroll
    for (int n = 0; n < 4; n++)
      bw[n] = *(const bf16x8*)&Bs[bfi][(wn * 64 + n * 16 + (lane & 15)) * 32 + (lane >> 4) * 8];
#pragma unroll
    for (int m = 0; m < 4; m++)
#pragma unroll
      for (int n = 0; n < 4; n++)
        acc[m][n] = __builtin_amdgcn_mfma_f32_16x16x32_bf16(af[m], bw[n], acc[m][n], 0, 0, 0);
    __syncthreads();
    bfi ^= 1;
  }

  int cc[4];
  float bv[4];
#pragma unroll
  for (int n = 0; n < 4; n++) {
    cc[n] = col0 + wn * 64 + n * 16 + (lane & 15);
    bv[n] = bias[cc[n]];
  }
#pragma unroll
  for (int m = 0; m < 4; m++) {
    int rb = row0 + wm * 64 + m * 16 + ((lane >> 4) << 2);
#pragma unroll
    for (int j = 0; j < 4; j++) {
      int r = rb + j;
      if (r < M) {
#pragma unroll
        for (int n = 0; n < 4; n++) {
          float vv = acc[m][n][j] + bv[n];
          size_t off = (size_t)r * N + cc[n];
          if constexpr (EPI == 0) {
            ((u16*)outp)[off] = f2b(vv);
          } else if constexpr (EPI == 1) {
            ((float*)outp)[off] = vv + res[off];
          } else {
            ((u16*)outp)[off] = f2b(gelu_exact(vv));
          }
        }
      }
    }
  }
}

// ---------------- CLS-token attention: one block per (batch, head) ----------------
__global__ __launch_bounds__(256)
void cls_attn(const u16* __restrict__ qkv, u16* __restrict__ aout) {
  int b = blockIdx.x / kHeads, h = blockIdx.x % kHeads;
  __shared__ float lgs[kL];
  __shared__ float qs[32];
  __shared__ float red[8];
  __shared__ float part[8][32];
  int tid = threadIdx.x, lane = tid & 63, wv = tid >> 6;
  size_t rb = (size_t)b * kL;
  if (tid < 32) qs[tid] = b2f(qkv[rb * 1152 + h * 32 + tid]) * kScale;
  __syncthreads();
  float lmax = -1e30f;
  for (int t = tid; t < kL; t += 256) {
    const u16* kp = qkv + (rb + t) * 1152 + 384 + h * 32;
    float s = 0.f;
#pragma unroll
    for (int g4 = 0; g4 < 4; g4++) {
      uint4 u = *(const uint4*)(kp + g4 * 8);
      s += qs[g4*8+0]*blo(u.x) + qs[g4*8+1]*bhi(u.x)
         + qs[g4*8+2]*blo(u.y) + qs[g4*8+3]*bhi(u.y)
         + qs[g4*8+4]*blo(u.z) + qs[g4*8+5]*bhi(u.z)
         + qs[g4*8+6]*blo(u.w) + qs[g4*8+7]*bhi(u.w);
    }
    lgs[t] = s;
    lmax = fmaxf(lmax, s);
  }
  lmax = wred_max(lmax);
  if (lane == 0) red[wv] = lmax;
  __syncthreads();
  float gmax = fmaxf(fmaxf(red[0], red[1]), fmaxf(red[2], red[3]));
  float lsum = 0.f;
  for (int t = tid; t < kL; t += 256) {
    float e = expf(lgs[t] - gmax);
    lgs[t] = e;
    lsum += e;
  }
  lsum = wred_sum(lsum);
  if (lane == 0) red[4 + wv] = lsum;
  __syncthreads();
  float rs = 1.f / (red[4] + red[5] + red[6] + red[7]);
  int d = tid & 31, grp = tid >> 5;
  float a = 0.f;
  for (int t = grp; t < kL; t += 8)
    a += lgs[t] * b2f(qkv[(rb + t) * 1152 + 768 + h * 32 + d]);
  part[grp][d] = a;
  __syncthreads();
  if (tid < 32) {
    float o = 0.f;
#pragma unroll
    for (int g = 0; g < 8; g++) o += part[g][tid];
    aout[rb * 384 + h * 32 + tid] = f2b(o * rs);
  }
}

// ---------------- shifted-window attention: one wave per (window, head) ----------------
// 49 queries x 50 keys (key 0 = CLS). Rel-bias + region mask computed in-kernel.
__global__ __launch_bounds__(64)
void win_attn(const u16* __restrict__ qkv, const float* __restrict__ relb,
              u16* __restrict__ aout) {
  int bid = blockIdx.x;
  int h = bid % kHeads;
  int w = (bid / kHeads) & 63;
  int b = bid / (kHeads * 64);
  int wi = w >> 3, wj = w & 7;
  int lane = threadIdx.x;
  __shared__ __align__(16) float KS[50 * 32];
  __shared__ __align__(16) float VS[50 * 32];
  __shared__ float BIA[169];
  __shared__ int ROWS[50];
  __shared__ int REGN[50];
  if (lane < 50) {
    int row, reg;
    if (lane == 0) {
      row = b * kL;            // CLS token row
      reg = -1;
    } else {
      int n = lane - 1, i = n / 7, j = n % 7;
      int r = wi * 7 + i, c = wj * 7 + j;               // rolled-canvas coords
      reg = (r < 49 ? 0 : (r < 53 ? 1 : 2)) * 3 + (c < 49 ? 0 : (c < 53 ? 1 : 2));
      int orr = r + 3; if (orr >= 56) orr -= 56;        // un-rolled (original) coords
      int occ = c + 3; if (occ >= 56) occ -= 56;
      row = b * kL + 1 + orr * 56 + occ;
    }
    ROWS[lane] = row;
    REGN[lane] = reg;
  }
  for (int i = lane; i < 169; i += 64) BIA[i] = relb[i * 12 + h];
  __syncthreads();
  // stage K,V (50 tokens x 32 dims) as f32
  for (int idx = lane; idx < 200; idx += 64) {
    int tok = idx >> 2, g4 = idx & 3;
    const u16* base = qkv + (size_t)ROWS[tok] * 1152 + h * 32 + g4 * 8;
    uint4 uk = *(const uint4*)(base + 384);
    uint4 uv = *(const uint4*)(base + 768);
    float* kd = &KS[tok * 32 + g4 * 8];
    float* vd = &VS[tok * 32 + g4 * 8];
    kd[0]=blo(uk.x); kd[1]=bhi(uk.x); kd[2]=blo(uk.y); kd[3]=bhi(uk.y);
    kd[4]=blo(uk.z); kd[5]=bhi(uk.z); kd[6]=blo(uk.w); kd[7]=bhi(uk.w);
    vd[0]=blo(uv.x); vd[1]=bhi(uv.x); vd[2]=blo(uv.y); vd[3]=bhi(uv.y);
    vd[4]=blo(uv.z); vd[5]=bhi(uv.z); vd[6]=blo(uv.w); vd[7]=bhi(uv.w);
  }
  __syncthreads();
  if (lane >= 49) return;
  float qr[32];
  {
    const u16* qp = qkv + (size_t)ROWS[lane + 1] * 1152 + h * 32;
#pragma unroll
    for (int g4 = 0; g4 < 4; g4++) {
      uint4 u = *(const uint4*)(qp + g4 * 8);
      qr[g4*8+0]=blo(u.x)*kScale; qr[g4*8+1]=bhi(u.x)*kScale;
      qr[g4*8+2]=blo(u.y)*kScale; qr[g4*8+3]=bhi(u.y)*kScale;
      qr[g4*8+4]=blo(u.z)*kScale; qr[g4*8+5]=bhi(u.z)*kScale;
      qr[g4*8+6]=blo(u.w)*kScale; qr[g4*8+7]=bhi(u.w)*kScale;
    }
  }
  int qi = lane / 7, qj = lane % 7;
  int rq = REGN[lane + 1];
  int qb = qi * 13 + qj;
  float lg[50];
#pragma unroll
  for (int k = 0; k < 50; k++) {
    float s = 0.f;
#pragma unroll
    for (int d4 = 0; d4 < 8; d4++) {
      float4 kv = *(const float4*)&KS[k * 32 + d4 * 4];
      s = fmaf(qr[d4*4+0], kv.x, s);
      s = fmaf(qr[d4*4+1], kv.y, s);
      s = fmaf(qr[d4*4+2], kv.z, s);
      s = fmaf(qr[d4*4+3], kv.w, s);
    }
    if (k > 0) {
      const int ki = (k - 1) / 7, kj = (k - 1) % 7;     // compile-time (unrolled)
      s += BIA[qb + (6 - ki) * 13 + (6 - kj)];
      if (REGN[k] != rq) s -= 100.f;
    }
    lg[k] = s;
  }
  float mx = lg[0];
#pragma unroll
  for (int k = 1; k < 50; k++) mx = fmaxf(mx, lg[k]);
  float ssum = 0.f;
#pragma unroll
  for (int k = 0; k < 50; k++) { lg[k] = expf(lg[k] - mx); ssum += lg[k]; }
  float rs = 1.f / ssum;
  float4 o4[8];
#pragma unroll
  for (int d4 = 0; d4 < 8; d4++) o4[d4] = make_float4(0.f, 0.f, 0.f, 0.f);
#pragma unroll
  for (int k = 0; k < 50; k++) {
    float p = lg[k];
#pragma unroll
    for (int d4 = 0; d4 < 8; d4++) {
      float4 v = *(const float4*)&VS[k * 32 + d4 * 4];
      o4[d4].x = fmaf(p, v.x, o4[d4].x);
      o4[d4].y = fmaf(p, v.y, o4[d4].y);
      o4[d4].z = fmaf(p, v.z, o4[d4].z);
      o4[d4].w = fmaf(p, v.w, o4[d4].w);
    }
  }
  u16* op = aout + (size_t)ROWS[lane + 1] * 384 + h * 32;
#pragma unroll
  for (int d4 = 0; d4 < 8; d4++) {
    ushort4 pk;
    pk.x = f2b(o4[d4].x * rs);
    pk.y = f2b(o4[d4].y * rs);
    pk.z = f2b(o4[d4].z * rs);
    pk.w = f2b(o4[d4].w * rs);
    *(ushort4*)(op + d4 * 4) = pk;
  }
}

// ---------------- launcher ----------------
extern "C" void kernel_launch(void* const* d_in, const int* in_sizes, int n_in,
                              void* d_out, int out_size, void* d_ws, size_t ws_size,
                              hipStream_t stream) {
  const float* x      = (const float*)d_in[0];
  const float* n1g    = (const float*)d_in[1];
  const float* n1b    = (const float*)d_in[2];
  const float* qkv_w  = (const float*)d_in[3];
  const float* qkv_b  = (const float*)d_in[4];
  const float* relb   = (const float*)d_in[5];
  const float* proj_w = (const float*)d_in[6];
  const float* proj_b = (const float*)d_in[7];
  const float* n2g    = (const float*)d_in[8];
  const float* n2b    = (const float*)d_in[9];
  const float* fc1_w  = (const float*)d_in[10];
  const float* fc1_b  = (const float*)d_in[11];
  const float* fc2_w  = (const float*)d_in[12];
  const float* fc2_b  = (const float*)d_in[13];
  float* out = (float*)d_out;
  char* ws = (char*)d_ws;

  // workspace layout (total ~312 MB); x1 lives in d_out
  u16* wqkv  = (u16*)(ws + 0);                       //  884,736 B
  u16* wproj = (u16*)(ws + 884736);                  //  294,912 B
  u16* wfc1  = (u16*)(ws + 1179648);                 // 1,179,648 B
  u16* wfc2  = (u16*)(ws + 2359296);                 // 1,179,648 B
  u16* qkvb  = (u16*)(ws + 3538944);                 // 231,284,736 B (dead after attention)
  u16* h2b   = (u16*)(ws + 3538944);                 // reuse: LN2 chunk out (38.5 MB)
  u16* gb    = (u16*)(ws + 3538944 + 41943040);      // reuse: fc1 chunk out (154.2 MB)
  u16* hbuf  = (u16*)(ws + 234823680);               // 77,094,912 B (h, then attn_out)

  cvt_bf16<<<dim3((442368 + 255) / 256), 256, 0, stream>>>(qkv_w, wqkv, 442368);
  cvt_bf16<<<dim3((147456 + 255) / 256), 256, 0, stream>>>(proj_w, wproj, 147456);
  cvt_bf16<<<dim3((589824 + 255) / 256), 256, 0, stream>>>(fc1_w, wfc1, 589824);
  cvt_bf16<<<dim3((589824 + 255) / 256), 256, 0, stream>>>(fc2_w, wfc2, 589824);

  ln384<<<kM, 64, 0, stream>>>(x, n1g, n1b, hbuf, kM);
  gemm_bt<0><<<dim3(9, 785), 256, 0, stream>>>(hbuf, wqkv, qkv_b, nullptr, qkvb, kM, 1152, 384);
  cls_attn<<<kB * kHeads, 256, 0, stream>>>(qkvb, hbuf);
  win_attn<<<kB * 64 * kHeads, 64, 0, stream>>>(qkvb, relb, hbuf);
  gemm_bt<1><<<dim3(3, 785), 256, 0, stream>>>(hbuf, wproj, proj_b, x, out, kM, 384, 384);

  for (int c = 0; c < 2; c++) {
    int r0 = c * 50192, nr = 50192;
    ln384<<<nr, 64, 0, stream>>>(out + (size_t)r0 * 384, n2g, n2b, h2b, nr);
    gemm_bt<2><<<dim3(12, 393), 256, 0, stream>>>(h2b, wfc1, fc1_b, nullptr, gb, nr, 1536, 384);
    gemm_bt<1><<<dim3(3, 393), 256, 0, stream>>>(gb, wfc2, fc2_b, out + (size_t)r0 * 384,
                                                 out + (size_t)r0 * 384, nr, 384, 1536);
  }
}

// Round 2
// 1137.934 us; speedup vs baseline: 1.1254x; 1.1254x over previous
//
#include <hip/hip_runtime.h>

#define DEVI __device__ __forceinline__

typedef __attribute__((ext_vector_type(8))) __bf16 bf16x8;
typedef __attribute__((ext_vector_type(4))) float f32x4;
typedef unsigned short u16;
typedef unsigned int u32;

static constexpr int kB = 32;
static constexpr int kL = 3137;           // 56*56+1
static constexpr int kM = kB * kL;        // 100384 rows total
static constexpr int kHeads = 12;
static constexpr float kScale = 0.17677669529663687f;  // 32^-0.5

DEVI u16 f2b(float f) {                   // f32 -> bf16 RNE
  u32 u = __float_as_uint(f);
  u32 r = (u + 0x7fffu + ((u >> 16) & 1u)) >> 16;
  return (u16)r;
}
DEVI float blo(u32 u) { return __uint_as_float(u << 16); }
DEVI float bhi(u32 u) { return __uint_as_float(u & 0xffff0000u); }
DEVI float b2f(u16 h) { return __uint_as_float(((u32)h) << 16); }

DEVI void async16(const void* g, void* l) {
  __builtin_amdgcn_global_load_lds((const __attribute__((address_space(1))) u32*)g,
                                   (__attribute__((address_space(3))) u32*)l, 16, 0, 0);
}

DEVI float wred_max(float v) {
#pragma unroll
  for (int o = 32; o; o >>= 1) v = fmaxf(v, __shfl_xor(v, o));
  return v;
}
DEVI float wred_sum(float v) {
#pragma unroll
  for (int o = 32; o; o >>= 1) v += __shfl_xor(v, o);
  return v;
}

// ---------------- weight f32 -> bf16 ----------------
__global__ void cvt_bf16(const float* __restrict__ in, u16* __restrict__ out, int n) {
  int i = blockIdx.x * 256 + threadIdx.x;
  if (i < n) out[i] = f2b(in[i]);
}

// ---------------- LayerNorm over 384, one wave per row, bf16 out ----------------
__global__ __launch_bounds__(64)
void ln384(const float* __restrict__ x, const float* __restrict__ g,
           const float* __restrict__ b, u16* __restrict__ out, int rows) {
  int row = blockIdx.x;
  if (row >= rows) return;
  const float* xr = x + (size_t)row * 384;
  int t = threadIdx.x;
  float v[6], s = 0.f, s2 = 0.f;
#pragma unroll
  for (int i = 0; i < 6; i++) {
    v[i] = xr[t + 64 * i];
    s += v[i];
    s2 += v[i] * v[i];
  }
  s = wred_sum(s);
  s2 = wred_sum(s2);
  float mean = s * (1.f / 384.f);
  float var = s2 * (1.f / 384.f) - mean * mean;
  float rinv = rsqrtf(var + 1e-5f);
  u16* orow = out + (size_t)row * 384;
#pragma unroll
  for (int i = 0; i < 6; i++) {
    int c = t + 64 * i;
    orow[c] = f2b((v[i] - mean) * rinv * g[c] + b[c]);
  }
}

DEVI float gelu_exact(float v) { return 0.5f * v * (1.f + erff(v * 0.70710678118654752f)); }

// ---------------- bf16 MFMA GEMM:  out = A(MxK) @ W(NxK)^T + bias [+res] ----------------
// 128x128 tile, BK=32, 4 waves (2x2), each wave 4x4 frags of 16x16x32.
// EPI: 0 = bias -> bf16 ; 1 = bias + res -> f32 ; 2 = bias + gelu -> bf16
template <int EPI>
__global__ __launch_bounds__(256)
void gemm_bt(const u16* __restrict__ A, const u16* __restrict__ W,
             const float* __restrict__ bias, const float* __restrict__ res,
             void* __restrict__ outp, int M, int N, int K) {
  const int tid = threadIdx.x, lane = tid & 63, wv = tid >> 6;
  const int col0 = blockIdx.x * 128, row0 = blockIdx.y * 128;
  __shared__ __align__(16) u16 As[2][128 * 32];
  __shared__ __align__(16) u16 Bs[2][128 * 32];
  f32x4 acc[4][4];
  f32x4 zero = {0.f, 0.f, 0.f, 0.f};
#pragma unroll
  for (int m = 0; m < 4; m++)
#pragma unroll
    for (int n = 0; n < 4; n++) acc[m][n] = zero;
  const int wm = wv >> 1, wn = wv & 1;
  const int NT = K >> 5;

  auto stage = [&](int kt, int bfi) {
#pragma unroll
    for (int s = 0; s < 2; s++) {
      int ch = wv * 2 + s;                     // 8 chunks of 16 rows x 64B
      int r = ch * 16 + (lane >> 2);
      int kk = kt * 32 + (lane & 3) * 8;
      const u16* gp = A + (size_t)min(row0 + r, M - 1) * K + kk;
      async16(gp, &As[bfi][ch * 512]);         // wave-uniform LDS base + lane*16B
      const u16* gq = W + (size_t)min(col0 + r, N - 1) * K + kk;
      async16(gq, &Bs[bfi][ch * 512]);
    }
  };

  stage(0, 0);
  __syncthreads();
  int bfi = 0;
  for (int kt = 0; kt < NT; ++kt) {
    if (kt + 1 < NT) stage(kt + 1, bfi ^ 1);
    bf16x8 af[4], bw[4];
#pragma unroll
    for (int m = 0; m < 4; m++)
      af[m] = *(const bf16x8*)&As[bfi][(wm * 64 + m * 16 + (lane & 15)) * 32 + (lane >> 4) * 8];
#pragma unroll
    for (int n = 0; n < 4; n++)
      bw[n] = *(const bf16x8*)&Bs[bfi][(wn * 64 + n * 16 + (lane & 15)) * 32 + (lane >> 4) * 8];
#pragma unroll
    for (int m = 0; m < 4; m++)
#pragma unroll
      for (int n = 0; n < 4; n++)
        acc[m][n] = __builtin_amdgcn_mfma_f32_16x16x32_bf16(af[m], bw[n], acc[m][n], 0, 0, 0);
    __syncthreads();
    bfi ^= 1;
  }

  int cc[4];
  float bv[4];
#pragma unroll
  for (int n = 0; n < 4; n++) {
    cc[n] = col0 + wn * 64 + n * 16 + (lane & 15);
    bv[n] = bias[cc[n]];
  }
#pragma unroll
  for (int m = 0; m < 4; m++) {
    int rb = row0 + wm * 64 + m * 16 + ((lane >> 4) << 2);
#pragma unroll
    for (int j = 0; j < 4; j++) {
      int r = rb + j;
      if (r < M) {
#pragma unroll
        for (int n = 0; n < 4; n++) {
          float vv = acc[m][n][j] + bv[n];
          size_t off = (size_t)r * N + cc[n];
          if constexpr (EPI == 0) {
            ((u16*)outp)[off] = f2b(vv);
          } else if constexpr (EPI == 1) {
            ((float*)outp)[off] = vv + res[off];
          } else {
            ((u16*)outp)[off] = f2b(gelu_exact(vv));
          }
        }
      }
    }
  }
}

// ---------------- CLS-token attention: one block per (batch, head) ----------------
__global__ __launch_bounds__(256)
void cls_attn(const u16* __restrict__ qkv, u16* __restrict__ aout) {
  int b = blockIdx.x / kHeads, h = blockIdx.x % kHeads;
  __shared__ float lgs[kL];
  __shared__ float qs[32];
  __shared__ float red[8];
  __shared__ float part[8][32];
  int tid = threadIdx.x, lane = tid & 63, wv = tid >> 6;
  size_t rb = (size_t)b * kL;
  if (tid < 32) qs[tid] = b2f(qkv[rb * 1152 + h * 32 + tid]) * kScale;
  __syncthreads();
  float lmax = -1e30f;
  for (int t = tid; t < kL; t += 256) {
    const u16* kp = qkv + (rb + t) * 1152 + 384 + h * 32;
    float s = 0.f;
#pragma unroll
    for (int g4 = 0; g4 < 4; g4++) {
      uint4 u = *(const uint4*)(kp + g4 * 8);
      s += qs[g4*8+0]*blo(u.x) + qs[g4*8+1]*bhi(u.x)
         + qs[g4*8+2]*blo(u.y) + qs[g4*8+3]*bhi(u.y)
         + qs[g4*8+4]*blo(u.z) + qs[g4*8+5]*bhi(u.z)
         + qs[g4*8+6]*blo(u.w) + qs[g4*8+7]*bhi(u.w);
    }
    lgs[t] = s;
    lmax = fmaxf(lmax, s);
  }
  lmax = wred_max(lmax);
  if (lane == 0) red[wv] = lmax;
  __syncthreads();
  float gmax = fmaxf(fmaxf(red[0], red[1]), fmaxf(red[2], red[3]));
  float lsum = 0.f;
  for (int t = tid; t < kL; t += 256) {
    float e = expf(lgs[t] - gmax);
    lgs[t] = e;
    lsum += e;
  }
  lsum = wred_sum(lsum);
  if (lane == 0) red[4 + wv] = lsum;
  __syncthreads();
  float rs = 1.f / (red[4] + red[5] + red[6] + red[7]);
  int d = tid & 31, grp = tid >> 5;
  float a = 0.f;
  for (int t = grp; t < kL; t += 8)
    a += lgs[t] * b2f(qkv[(rb + t) * 1152 + 768 + h * 32 + d]);
  part[grp][d] = a;
  __syncthreads();
  if (tid < 32) {
    float o = 0.f;
#pragma unroll
    for (int g = 0; g < 8; g++) o += part[g][tid];
    aout[rb * 384 + h * 32 + tid] = f2b(o * rs);
  }
}

// ---------------- precompute bias_full[class][head][k][q] (64x64 per pair) ----------------
// k=0: CLS key (no bias/mask). k in [1,50): rel bias + region mask. k>=50: -1e9 (pad kill).
__global__ __launch_bounds__(256)
void bias_pre(const float* __restrict__ relb, float* __restrict__ bf) {
  int blk = blockIdx.x;           // cls*12 + h
  int cls = blk / 12, h = blk % 12;
  int clsH = (cls >> 1) & 1, clsW = cls & 1;
  for (int idx = threadIdx.x; idx < 4096; idx += 256) {
    int k = idx >> 6, q = idx & 63;
    float v = 0.f;
    if (k >= 50) {
      v = -1e9f;
    } else if (k >= 1 && q < 49) {
      int kt = k - 1, ki = kt / 7, kj = kt % 7;
      int qi = q / 7, qj = q % 7;
      v = relb[((qi - ki + 6) * 13 + (qj - kj + 6)) * 12 + h];
      int rq = (clsH ? (qi < 4 ? 1 : 2) : 0) * 3 + (clsW ? (qj < 4 ? 1 : 2) : 0);
      int rk = (clsH ? (ki < 4 ? 1 : 2) : 0) * 3 + (clsW ? (kj < 4 ? 1 : 2) : 0);
      if (rq != rk) v -= 100.f;
    }
    bf[(size_t)blk * 4096 + idx] = v;
  }
}

// ---------------- shifted-window attention, MFMA version ----------------
// 1 wave per (window, head), 4 waves/block. Swapped QK^T (S^T = mfma(K,Q)),
// in-register softmax per q-column, cvt_pk + shfl to PV A-fragments, MFMA PV
// against LDS-transposed V.
__global__ __launch_bounds__(256)
void win_attn2(const u16* __restrict__ qkv, const float* __restrict__ biasf,
               u16* __restrict__ aout) {
  const int tid = threadIdx.x, lane = tid & 63, wv = tid >> 6;
  const int gid = blockIdx.x * 4 + wv;
  const int h = gid % 12;
  const int wr = gid / 12;        // 0..2047
  const int win = wr & 63, b = wr >> 6;
  const int wi = win >> 3, wj = win & 7;
  const int cls = ((wi == 7) ? 2 : 0) + ((wj == 7) ? 1 : 0);
  const int c = lane & 15, g = lane >> 4;

  // per-wave LDS slices; strides chosen for uniform bank-group spread on b128
  __shared__ __align__(16) u16 KS[4][64 * 40];   // K row-major, row stride 40 u16 (80B)
  __shared__ __align__(16) u16 VT[4][32 * 72];   // V transposed [d][tok], stride 72 u16
  __shared__ int RW[4][52];
  u16* Ks = KS[wv];
  u16* Vt = VT[wv];
  int* Rows = RW[wv];

  // ---- staging: tasks (tok 0..63) x (half 0..1), 2 iters ----
#pragma unroll
  for (int it = 0; it < 2; ++it) {
    int idx = it * 64 + lane;
    int tok = idx >> 1, half = idx & 1;
    if (tok < 50) {
      int row;
      if (tok == 0) {
        row = b * kL;                                  // CLS
      } else {
        int n = tok - 1;
        int i = n / 7, j = n % 7;
        int r = wi * 7 + i, c2 = wj * 7 + j;           // rolled-canvas coords
        int orr = r + 3; if (orr >= 56) orr -= 56;     // original coords
        int occ = c2 + 3; if (occ >= 56) occ -= 56;
        row = b * kL + 1 + orr * 56 + occ;
      }
      if (half == 0) Rows[tok] = row;
      const u16* base = qkv + (size_t)row * 1152 + h * 32 + half * 16;
      uint4 k0 = *(const uint4*)(base + 384);
      uint4 k1 = *(const uint4*)(base + 384 + 8);
      *(uint4*)&Ks[tok * 40 + half * 16] = k0;
      *(uint4*)&Ks[tok * 40 + half * 16 + 8] = k1;
      uint4 v0 = *(const uint4*)(base + 768);
      uint4 v1 = *(const uint4*)(base + 768 + 8);
      u32 vw[8] = {v0.x, v0.y, v0.z, v0.w, v1.x, v1.y, v1.z, v1.w};
#pragma unroll
      for (int m = 0; m < 8; ++m) {                    // dims d = half*16 + 2m{,+1}
        Vt[(half * 16 + m * 2 + 0) * 72 + tok] = (u16)(vw[m] & 0xffffu);
        Vt[(half * 16 + m * 2 + 1) * 72 + tok] = (u16)(vw[m] >> 16);
      }
    } else {                                           // pad rows/cols -> zero
      uint4 z = {0u, 0u, 0u, 0u};
      *(uint4*)&Ks[tok * 40 + half * 16] = z;
      *(uint4*)&Ks[tok * 40 + half * 16 + 8] = z;
#pragma unroll
      for (int m = 0; m < 16; ++m) Vt[(half * 16 + m) * 72 + tok] = 0;
    }
  }
  __syncthreads();

  // ---- Q fragments (B-operand): lane holds Q[q = nt*16+c][d = g*8 .. +7] ----
  bf16x8 qf[4];
#pragma unroll
  for (int nt = 0; nt < 4; ++nt) {
    int q = nt * 16 + c;
    if (q > 48) q = 48;                                // clamp pad cols (discarded)
    const u16* qp = qkv + (size_t)Rows[q + 1] * 1152 + h * 32 + g * 8;
    qf[nt] = *(const bf16x8*)qp;
  }

  // ---- QK^T: S^T tiles. s[mt][nt]: row k=mt*16+g*4+reg, col q=nt*16+c ----
  f32x4 s[4][4];
  {
    f32x4 z = {0.f, 0.f, 0.f, 0.f};
    bf16x8 kf[4];
#pragma unroll
    for (int mt = 0; mt < 4; ++mt)
      kf[mt] = *(const bf16x8*)&Ks[(mt * 16 + c) * 40 + g * 8];
#pragma unroll
    for (int mt = 0; mt < 4; ++mt)
#pragma unroll
      for (int nt = 0; nt < 4; ++nt)
        s[mt][nt] = __builtin_amdgcn_mfma_f32_16x16x32_bf16(kf[mt], qf[nt], z, 0, 0, 0);
  }

  // ---- scale + bias + mask, softmax per q-column, normalize, pack to bf16 ----
  const float* bp = biasf + (size_t)(cls * 12 + h) * 4096;
  u32 wq[4][8];                                        // [nt][mt*2 + wbit]
#pragma unroll
  for (int nt = 0; nt < 4; ++nt) {
    float pv[16];
#pragma unroll
    for (int mt = 0; mt < 4; ++mt)
#pragma unroll
      for (int r = 0; r < 4; ++r)
        pv[mt * 4 + r] = s[mt][nt][r] * kScale + bp[(mt * 16 + g * 4 + r) * 64 + nt * 16 + c];
    float mx = pv[0];
#pragma unroll
    for (int i2 = 1; i2 < 16; ++i2) mx = fmaxf(mx, pv[i2]);
    mx = fmaxf(mx, __shfl_xor(mx, 16));
    mx = fmaxf(mx, __shfl_xor(mx, 32));
    float sum = 0.f;
#pragma unroll
    for (int i2 = 0; i2 < 16; ++i2) { pv[i2] = __expf(pv[i2] - mx); sum += pv[i2]; }
    sum += __shfl_xor(sum, 16);
    sum += __shfl_xor(sum, 32);
    float rs = 1.f / sum;
#pragma unroll
    for (int i2 = 0; i2 < 16; ++i2) pv[i2] *= rs;
#pragma unroll
    for (int mt = 0; mt < 4; ++mt) {
      u32 w0, w1;
      asm("v_cvt_pk_bf16_f32 %0, %1, %2" : "=v"(w0) : "v"(pv[mt * 4 + 0]), "v"(pv[mt * 4 + 1]));
      asm("v_cvt_pk_bf16_f32 %0, %1, %2" : "=v"(w1) : "v"(pv[mt * 4 + 2]), "v"(pv[mt * 4 + 3]));
      wq[nt][mt * 2 + 0] = w0;
      wq[nt][mt * 2 + 1] = w1;
    }
  }

  // ---- shuffle P words into PV A-fragments ----
  // target (mt2, ks, wj2): k-pair = ks*32 + g*8 + 2*wj2, q = mt2*16 + c
  // source lane (g_src = (g&1)*2 + (wj2>>1), c); word wq[mt2][mt_src*2 + (wj2&1)],
  // mt_src = 2ks + (g>>1)  -> two shfls (mt_src 2ks / 2ks+1) + select by g.
  bf16x8 pa[4][2];
#pragma unroll
  for (int mt2 = 0; mt2 < 4; ++mt2)
#pragma unroll
    for (int ks = 0; ks < 2; ++ks) {
      union { u32 u[4]; bf16x8 v; } cvt;
#pragma unroll
      for (int wj2 = 0; wj2 < 4; ++wj2) {
        int srcLane = c + 16 * (((g & 1) << 1) + (wj2 >> 1));
        u32 a0 = (u32)__shfl((int)wq[mt2][(2 * ks + 0) * 2 + (wj2 & 1)], srcLane);
        u32 a1 = (u32)__shfl((int)wq[mt2][(2 * ks + 1) * 2 + (wj2 & 1)], srcLane);
        cvt.u[wj2] = (g < 2) ? a0 : a1;
      }
      pa[mt2][ks] = cvt.v;
    }

  // ---- PV: O = P @ V via mfma(pa, vf); vf = V^T[d = ntd*16+c][k-chunk] ----
  f32x4 o[4][2];
  f32x4 z2 = {0.f, 0.f, 0.f, 0.f};
#pragma unroll
  for (int mt2 = 0; mt2 < 4; ++mt2)
#pragma unroll
    for (int ntd = 0; ntd < 2; ++ntd) o[mt2][ntd] = z2;
#pragma unroll
  for (int ks = 0; ks < 2; ++ks) {
    bf16x8 vf[2];
#pragma unroll
    for (int ntd = 0; ntd < 2; ++ntd)
      vf[ntd] = *(const bf16x8*)&Vt[(ntd * 16 + c) * 72 + ks * 32 + g * 8];
#pragma unroll
    for (int mt2 = 0; mt2 < 4; ++mt2)
#pragma unroll
      for (int ntd = 0; ntd < 2; ++ntd)
        o[mt2][ntd] = __builtin_amdgcn_mfma_f32_16x16x32_bf16(pa[mt2][ks], vf[ntd], o[mt2][ntd], 0, 0, 0);
  }

  // ---- epilogue: O row q = mt2*16+g*4+reg, col d = ntd*16+c ----
#pragma unroll
  for (int mt2 = 0; mt2 < 4; ++mt2)
#pragma unroll
    for (int r = 0; r < 4; ++r) {
      int q = mt2 * 16 + g * 4 + r;
      if (q < 49) {
        int row = Rows[q + 1];
        u16* op = aout + (size_t)row * 384 + h * 32 + c;
        op[0]  = f2b(o[mt2][0][r]);
        op[16] = f2b(o[mt2][1][r]);
      }
    }
}

// ---------------- launcher ----------------
extern "C" void kernel_launch(void* const* d_in, const int* in_sizes, int n_in,
                              void* d_out, int out_size, void* d_ws, size_t ws_size,
                              hipStream_t stream) {
  const float* x      = (const float*)d_in[0];
  const float* n1g    = (const float*)d_in[1];
  const float* n1b    = (const float*)d_in[2];
  const float* qkv_w  = (const float*)d_in[3];
  const float* qkv_b  = (const float*)d_in[4];
  const float* relb   = (const float*)d_in[5];
  const float* proj_w = (const float*)d_in[6];
  const float* proj_b = (const float*)d_in[7];
  const float* n2g    = (const float*)d_in[8];
  const float* n2b    = (const float*)d_in[9];
  const float* fc1_w  = (const float*)d_in[10];
  const float* fc1_b  = (const float*)d_in[11];
  const float* fc2_w  = (const float*)d_in[12];
  const float* fc2_b  = (const float*)d_in[13];
  float* out = (float*)d_out;
  char* ws = (char*)d_ws;

  // workspace layout (total ~312 MB); x1 lives in d_out
  u16* wqkv  = (u16*)(ws + 0);                       //  884,736 B (dead after qkv GEMM)
  float* biasf = (float*)(ws + 0);                   //  786,432 B (reuses wqkv region)
  u16* wproj = (u16*)(ws + 884736);                  //  294,912 B
  u16* wfc1  = (u16*)(ws + 1179648);                 // 1,179,648 B
  u16* wfc2  = (u16*)(ws + 2359296);                 // 1,179,648 B
  u16* qkvb  = (u16*)(ws + 3538944);                 // 231,284,736 B (dead after attention)
  u16* h2b   = (u16*)(ws + 3538944);                 // reuse: LN2 chunk out (38.5 MB)
  u16* gb    = (u16*)(ws + 3538944 + 41943040);      // reuse: fc1 chunk out (154.2 MB)
  u16* hbuf  = (u16*)(ws + 234823680);               // 77,094,912 B (h, then attn_out)

  cvt_bf16<<<dim3((442368 + 255) / 256), 256, 0, stream>>>(qkv_w, wqkv, 442368);
  cvt_bf16<<<dim3((147456 + 255) / 256), 256, 0, stream>>>(proj_w, wproj, 147456);
  cvt_bf16<<<dim3((589824 + 255) / 256), 256, 0, stream>>>(fc1_w, wfc1, 589824);
  cvt_bf16<<<dim3((589824 + 255) / 256), 256, 0, stream>>>(fc2_w, wfc2, 589824);

  ln384<<<kM, 64, 0, stream>>>(x, n1g, n1b, hbuf, kM);
  gemm_bt<0><<<dim3(9, 785), 256, 0, stream>>>(hbuf, wqkv, qkv_b, nullptr, qkvb, kM, 1152, 384);
  bias_pre<<<48, 256, 0, stream>>>(relb, biasf);     // into dead wqkv region
  cls_attn<<<kB * kHeads, 256, 0, stream>>>(qkvb, hbuf);
  win_attn2<<<kB * 64 * kHeads / 4, 256, 0, stream>>>(qkvb, biasf, hbuf);
  gemm_bt<1><<<dim3(3, 785), 256, 0, stream>>>(hbuf, wproj, proj_b, x, out, kM, 384, 384);

  for (int c = 0; c < 2; c++) {
    int r0 = c * 50192, nr = 50192;
    ln384<<<nr, 64, 0, stream>>>(out + (size_t)r0 * 384, n2g, n2b, h2b, nr);
    gemm_bt<2><<<dim3(12, 393), 256, 0, stream>>>(h2b, wfc1, fc1_b, nullptr, gb, nr, 1536, 384);
    gemm_bt<1><<<dim3(3, 393), 256, 0, stream>>>(gb, wfc2, fc2_b, out + (size_t)r0 * 384,
                                                 out + (size_t)r0 * 384, nr, 384, 1536);
  }
}

// Round 3
// 1015.515 us; speedup vs baseline: 1.2610x; 1.1205x over previous
//
#include <hip/hip_runtime.h>

#define DEVI __device__ __forceinline__

typedef __attribute__((ext_vector_type(8))) __bf16 bf16x8;
typedef __attribute__((ext_vector_type(4))) float f32x4;
typedef unsigned short u16;
typedef unsigned int u32;

static constexpr int kB = 32;
static constexpr int kL = 3137;           // 56*56+1
static constexpr int kM = kB * kL;        // 100384 rows total
static constexpr int kHeads = 12;
static constexpr float kScale = 0.17677669529663687f;  // 32^-0.5
static constexpr int kNC = 13;            // CLS key chunks of 256 (13*256 >= 3137)

DEVI u16 f2b(float f) {                   // f32 -> bf16 RNE
  u32 u = __float_as_uint(f);
  u32 r = (u + 0x7fffu + ((u >> 16) & 1u)) >> 16;
  return (u16)r;
}
DEVI float blo(u32 u) { return __uint_as_float(u << 16); }
DEVI float bhi(u32 u) { return __uint_as_float(u & 0xffff0000u); }
DEVI float b2f(u16 h) { return __uint_as_float(((u32)h) << 16); }

DEVI void async16(const void* g, void* l) {
  __builtin_amdgcn_global_load_lds((const __attribute__((address_space(1))) u32*)g,
                                   (__attribute__((address_space(3))) u32*)l, 16, 0, 0);
}

DEVI float wred_max(float v) {
#pragma unroll
  for (int o = 32; o; o >>= 1) v = fmaxf(v, __shfl_xor(v, o));
  return v;
}
DEVI float wred_sum(float v) {
#pragma unroll
  for (int o = 32; o; o >>= 1) v += __shfl_xor(v, o);
  return v;
}

// ---------------- weight f32 -> bf16 ----------------
__global__ void cvt_bf16(const float* __restrict__ in, u16* __restrict__ out, int n) {
  int i = blockIdx.x * 256 + threadIdx.x;
  if (i < n) out[i] = f2b(in[i]);
}

// ---------------- LayerNorm over 384, one wave per row, bf16 out ----------------
__global__ __launch_bounds__(64)
void ln384(const float* __restrict__ x, const float* __restrict__ g,
           const float* __restrict__ b, u16* __restrict__ out, int rows) {
  int row = blockIdx.x;
  if (row >= rows) return;
  const float* xr = x + (size_t)row * 384;
  int t = threadIdx.x;
  float v[6], s = 0.f, s2 = 0.f;
#pragma unroll
  for (int i = 0; i < 6; i++) {
    v[i] = xr[t + 64 * i];
    s += v[i];
    s2 += v[i] * v[i];
  }
  s = wred_sum(s);
  s2 = wred_sum(s2);
  float mean = s * (1.f / 384.f);
  float var = s2 * (1.f / 384.f) - mean * mean;
  float rinv = rsqrtf(var + 1e-5f);
  u16* orow = out + (size_t)row * 384;
#pragma unroll
  for (int i = 0; i < 6; i++) {
    int c = t + 64 * i;
    orow[c] = f2b((v[i] - mean) * rinv * g[c] + b[c]);
  }
}

DEVI float gelu_exact(float v) { return 0.5f * v * (1.f + erff(v * 0.70710678118654752f)); }

// ---------------- bf16 MFMA GEMM:  out = A(MxK) @ W(NxK)^T + bias [+res] ----------------
// 128x128 tile, BK=32, 4 waves (2x2), each wave 4x4 frags of 16x16x32.
// EPI: 0 = bias -> bf16 ; 1 = bias + res -> f32 ; 2 = bias + gelu -> bf16
template <int EPI>
__global__ __launch_bounds__(256)
void gemm_bt(const u16* __restrict__ A, const u16* __restrict__ W,
             const float* __restrict__ bias, const float* __restrict__ res,
             void* __restrict__ outp, int M, int N, int K) {
  const int tid = threadIdx.x, lane = tid & 63, wv = tid >> 6;
  const int col0 = blockIdx.x * 128, row0 = blockIdx.y * 128;
  __shared__ __align__(16) u16 As[2][128 * 32];
  __shared__ __align__(16) u16 Bs[2][128 * 32];
  f32x4 acc[4][4];
  f32x4 zero = {0.f, 0.f, 0.f, 0.f};
#pragma unroll
  for (int m = 0; m < 4; m++)
#pragma unroll
    for (int n = 0; n < 4; n++) acc[m][n] = zero;
  const int wm = wv >> 1, wn = wv & 1;
  const int NT = K >> 5;

  auto stage = [&](int kt, int bfi) {
#pragma unroll
    for (int s = 0; s < 2; s++) {
      int ch = wv * 2 + s;                     // 8 chunks of 16 rows x 64B
      int r = ch * 16 + (lane >> 2);
      int kk = kt * 32 + (lane & 3) * 8;
      const u16* gp = A + (size_t)min(row0 + r, M - 1) * K + kk;
      async16(gp, &As[bfi][ch * 512]);         // wave-uniform LDS base + lane*16B
      const u16* gq = W + (size_t)min(col0 + r, N - 1) * K + kk;
      async16(gq, &Bs[bfi][ch * 512]);
    }
  };

  stage(0, 0);
  __syncthreads();
  int bfi = 0;
  for (int kt = 0; kt < NT; ++kt) {
    if (kt + 1 < NT) stage(kt + 1, bfi ^ 1);
    bf16x8 af[4], bw[4];
#pragma unroll
    for (int m = 0; m < 4; m++)
      af[m] = *(const bf16x8*)&As[bfi][(wm * 64 + m * 16 + (lane & 15)) * 32 + (lane >> 4) * 8];
#pragma unroll
    for (int n = 0; n < 4; n++)
      bw[n] = *(const bf16x8*)&Bs[bfi][(wn * 64 + n * 16 + (lane & 15)) * 32 + (lane >> 4) * 8];
#pragma unroll
    for (int m = 0; m < 4; m++)
#pragma unroll
      for (int n = 0; n < 4; n++)
        acc[m][n] = __builtin_amdgcn_mfma_f32_16x16x32_bf16(af[m], bw[n], acc[m][n], 0, 0, 0);
    __syncthreads();
    bfi ^= 1;
  }

  int cc[4];
  float bv[4];
#pragma unroll
  for (int n = 0; n < 4; n++) {
    cc[n] = col0 + wn * 64 + n * 16 + (lane & 15);
    bv[n] = bias[cc[n]];
  }
#pragma unroll
  for (int m = 0; m < 4; m++) {
    int rb = row0 + wm * 64 + m * 16 + ((lane >> 4) << 2);
#pragma unroll
    for (int j = 0; j < 4; j++) {
      int r = rb + j;
      if (r < M) {
#pragma unroll
        for (int n = 0; n < 4; n++) {
          float vv = acc[m][n][j] + bv[n];
          size_t off = (size_t)r * N + cc[n];
          if constexpr (EPI == 0) {
            ((u16*)outp)[off] = f2b(vv);
          } else if constexpr (EPI == 1) {
            ((float*)outp)[off] = vv + res[off];
          } else {
            ((u16*)outp)[off] = f2b(gelu_exact(vv));
          }
        }
      }
    }
  }
}

// ---------------- CLS attention, flash-decode phase 1 ----------------
// grid (b*12+h, chunk); 256 threads; one key-token per thread.
// Writes partials [bh][chunk]: {m, expsum, o[32]} (34 floats).
__global__ __launch_bounds__(256)
void cls_part(const u16* __restrict__ qkv, float* __restrict__ parts) {
  int bh = blockIdx.x;
  int chunk = blockIdx.y;
  int b = bh / kHeads, h = bh % kHeads;
  __shared__ float qs[32];
  __shared__ float ps[256];
  __shared__ float red[8];
  __shared__ float part[8][32];
  int tid = threadIdx.x, lane = tid & 63, wv = tid >> 6;
  size_t rb = (size_t)b * kL;
  if (tid < 32) qs[tid] = b2f(qkv[rb * 1152 + h * 32 + tid]) * kScale;
  __syncthreads();
  int t0 = chunk * 256;
  int nTok = min(256, kL - t0);
  float s = -1e30f;
  if (tid < nTok) {
    const u16* kp = qkv + (rb + t0 + tid) * 1152 + 384 + h * 32;
    s = 0.f;
#pragma unroll
    for (int g4 = 0; g4 < 4; g4++) {
      uint4 u = *(const uint4*)(kp + g4 * 8);
      s += qs[g4*8+0]*blo(u.x) + qs[g4*8+1]*bhi(u.x)
         + qs[g4*8+2]*blo(u.y) + qs[g4*8+3]*bhi(u.y)
         + qs[g4*8+4]*blo(u.z) + qs[g4*8+5]*bhi(u.z)
         + qs[g4*8+6]*blo(u.w) + qs[g4*8+7]*bhi(u.w);
    }
  }
  float m = wred_max(s);
  if (lane == 0) red[wv] = m;
  __syncthreads();
  float gm = fmaxf(fmaxf(red[0], red[1]), fmaxf(red[2], red[3]));
  float p = (tid < nTok) ? __expf(s - gm) : 0.f;
  ps[tid] = p;
  float ls = wred_sum(p);
  if (lane == 0) red[4 + wv] = ls;
  __syncthreads();
  float tot = red[4] + red[5] + red[6] + red[7];
  // weighted V partial
  int d = tid & 31, g = tid >> 5;
  float a = 0.f;
  for (int t = g; t < nTok; t += 8)
    a += ps[t] * b2f(qkv[(rb + t0 + t) * 1152 + 768 + h * 32 + d]);
  part[g][d] = a;
  __syncthreads();
  if (tid < 32) {
    float o = 0.f;
#pragma unroll
    for (int g2 = 0; g2 < 8; g2++) o += part[g2][tid];
    float* pp = parts + ((size_t)bh * kNC + chunk) * 34;
    pp[2 + tid] = o;
    if (tid == 0) { pp[0] = gm; pp[1] = tot; }
  }
}

// ---------------- CLS attention, phase 2: LSE-merge 13 chunks ----------------
__global__ __launch_bounds__(64)
void cls_reduce(const float* __restrict__ parts, u16* __restrict__ aout) {
  int bh = blockIdx.x;
  int b = bh / kHeads, h = bh % kHeads;
  int tid = threadIdx.x;
  __shared__ float sm[kNC], ss[kNC];
  if (tid < kNC) {
    sm[tid] = parts[((size_t)bh * kNC + tid) * 34];
    ss[tid] = parts[((size_t)bh * kNC + tid) * 34 + 1];
  }
  __syncthreads();
  float M = -1e30f;
#pragma unroll
  for (int c = 0; c < kNC; c++) M = fmaxf(M, sm[c]);
  float W = 0.f;
#pragma unroll
  for (int c = 0; c < kNC; c++) W += ss[c] * __expf(sm[c] - M);
  if (tid < 32) {
    float o = 0.f;
#pragma unroll
    for (int c = 0; c < kNC; c++)
      o += parts[((size_t)bh * kNC + c) * 34 + 2 + tid] * __expf(sm[c] - M);
    aout[(size_t)b * kL * 384 + h * 32 + tid] = f2b(o / W);
  }
}

// ---------------- precompute bias_full[class][head][k][q] (64x64 per pair) ----------------
// k=0: CLS key (no bias/mask). k in [1,50): rel bias + region mask. k>=50: -1e9 (pad kill).
__global__ __launch_bounds__(256)
void bias_pre(const float* __restrict__ relb, float* __restrict__ bf) {
  int blk = blockIdx.x;           // cls*12 + h
  int cls = blk / 12, h = blk % 12;
  int clsH = (cls >> 1) & 1, clsW = cls & 1;
  for (int idx = threadIdx.x; idx < 4096; idx += 256) {
    int k = idx >> 6, q = idx & 63;
    float v = 0.f;
    if (k >= 50) {
      v = -1e9f;
    } else if (k >= 1 && q < 49) {
      int kt = k - 1, ki = kt / 7, kj = kt % 7;
      int qi = q / 7, qj = q % 7;
      v = relb[((qi - ki + 6) * 13 + (qj - kj + 6)) * 12 + h];
      int rq = (clsH ? (qi < 4 ? 1 : 2) : 0) * 3 + (clsW ? (qj < 4 ? 1 : 2) : 0);
      int rk = (clsH ? (ki < 4 ? 1 : 2) : 0) * 3 + (clsW ? (kj < 4 ? 1 : 2) : 0);
      if (rq != rk) v -= 100.f;
    }
    bf[(size_t)blk * 4096 + idx] = v;
  }
}

// ---------------- shifted-window attention, MFMA version ----------------
// 1 wave per (window, head), 4 waves/block. Swapped QK^T (S^T = mfma(K,Q)),
// in-register softmax per q-column, cvt_pk + shfl to PV A-fragments, MFMA PV
// against LDS-transposed V.
__global__ __launch_bounds__(256)
void win_attn2(const u16* __restrict__ qkv, const float* __restrict__ biasf,
               u16* __restrict__ aout) {
  const int tid = threadIdx.x, lane = tid & 63, wv = tid >> 6;
  const int gid = blockIdx.x * 4 + wv;
  const int h = gid % 12;
  const int wr = gid / 12;        // 0..2047
  const int win = wr & 63, b = wr >> 6;
  const int wi = win >> 3, wj = win & 7;
  const int cls = ((wi == 7) ? 2 : 0) + ((wj == 7) ? 1 : 0);
  const int c = lane & 15, g = lane >> 4;

  // per-wave LDS slices; strides chosen for uniform bank-group spread on b128
  __shared__ __align__(16) u16 KS[4][64 * 40];   // K row-major, row stride 40 u16 (80B)
  __shared__ __align__(16) u16 VT[4][32 * 72];   // V transposed [d][tok], stride 72 u16
  __shared__ int RW[4][52];
  u16* Ks = KS[wv];
  u16* Vt = VT[wv];
  int* Rows = RW[wv];

  // ---- staging: tasks (tok 0..63) x (half 0..1), 2 iters ----
#pragma unroll
  for (int it = 0; it < 2; ++it) {
    int idx = it * 64 + lane;
    int tok = idx >> 1, half = idx & 1;
    if (tok < 50) {
      int row;
      if (tok == 0) {
        row = b * kL;                                  // CLS
      } else {
        int n = tok - 1;
        int i = n / 7, j = n % 7;
        int r = wi * 7 + i, c2 = wj * 7 + j;           // rolled-canvas coords
        int orr = r + 3; if (orr >= 56) orr -= 56;     // original coords
        int occ = c2 + 3; if (occ >= 56) occ -= 56;
        row = b * kL + 1 + orr * 56 + occ;
      }
      if (half == 0) Rows[tok] = row;
      const u16* base = qkv + (size_t)row * 1152 + h * 32 + half * 16;
      uint4 k0 = *(const uint4*)(base + 384);
      uint4 k1 = *(const uint4*)(base + 384 + 8);
      *(uint4*)&Ks[tok * 40 + half * 16] = k0;
      *(uint4*)&Ks[tok * 40 + half * 16 + 8] = k1;
      uint4 v0 = *(const uint4*)(base + 768);
      uint4 v1 = *(const uint4*)(base + 768 + 8);
      u32 vw[8] = {v0.x, v0.y, v0.z, v0.w, v1.x, v1.y, v1.z, v1.w};
#pragma unroll
      for (int m = 0; m < 8; ++m) {                    // dims d = half*16 + 2m{,+1}
        Vt[(half * 16 + m * 2 + 0) * 72 + tok] = (u16)(vw[m] & 0xffffu);
        Vt[(half * 16 + m * 2 + 1) * 72 + tok] = (u16)(vw[m] >> 16);
      }
    } else {                                           // pad rows/cols -> zero
      uint4 z = {0u, 0u, 0u, 0u};
      *(uint4*)&Ks[tok * 40 + half * 16] = z;
      *(uint4*)&Ks[tok * 40 + half * 16 + 8] = z;
#pragma unroll
      for (int m = 0; m < 16; ++m) Vt[(half * 16 + m) * 72 + tok] = 0;
    }
  }
  __syncthreads();

  // ---- Q fragments (B-operand): lane holds Q[q = nt*16+c][d = g*8 .. +7] ----
  bf16x8 qf[4];
#pragma unroll
  for (int nt = 0; nt < 4; ++nt) {
    int q = nt * 16 + c;
    if (q > 48) q = 48;                                // clamp pad cols (discarded)
    const u16* qp = qkv + (size_t)Rows[q + 1] * 1152 + h * 32 + g * 8;
    qf[nt] = *(const bf16x8*)qp;
  }

  // ---- QK^T: S^T tiles. s[mt][nt]: row k=mt*16+g*4+reg, col q=nt*16+c ----
  f32x4 s[4][4];
  {
    f32x4 z = {0.f, 0.f, 0.f, 0.f};
    bf16x8 kf[4];
#pragma unroll
    for (int mt = 0; mt < 4; ++mt)
      kf[mt] = *(const bf16x8*)&Ks[(mt * 16 + c) * 40 + g * 8];
#pragma unroll
    for (int mt = 0; mt < 4; ++mt)
#pragma unroll
      for (int nt = 0; nt < 4; ++nt)
        s[mt][nt] = __builtin_amdgcn_mfma_f32_16x16x32_bf16(kf[mt], qf[nt], z, 0, 0, 0);
  }

  // ---- scale + bias + mask, softmax per q-column, normalize, pack to bf16 ----
  const float* bp = biasf + (size_t)(cls * 12 + h) * 4096;
  u32 wq[4][8];                                        // [nt][mt*2 + wbit]
#pragma unroll
  for (int nt = 0; nt < 4; ++nt) {
    float pv[16];
#pragma unroll
    for (int mt = 0; mt < 4; ++mt)
#pragma unroll
      for (int r = 0; r < 4; ++r)
        pv[mt * 4 + r] = s[mt][nt][r] * kScale + bp[(mt * 16 + g * 4 + r) * 64 + nt * 16 + c];
    float mx = pv[0];
#pragma unroll
    for (int i2 = 1; i2 < 16; ++i2) mx = fmaxf(mx, pv[i2]);
    mx = fmaxf(mx, __shfl_xor(mx, 16));
    mx = fmaxf(mx, __shfl_xor(mx, 32));
    float sum = 0.f;
#pragma unroll
    for (int i2 = 0; i2 < 16; ++i2) { pv[i2] = __expf(pv[i2] - mx); sum += pv[i2]; }
    sum += __shfl_xor(sum, 16);
    sum += __shfl_xor(sum, 32);
    float rs = 1.f / sum;
#pragma unroll
    for (int i2 = 0; i2 < 16; ++i2) pv[i2] *= rs;
#pragma unroll
    for (int mt = 0; mt < 4; ++mt) {
      u32 w0, w1;
      asm("v_cvt_pk_bf16_f32 %0, %1, %2" : "=v"(w0) : "v"(pv[mt * 4 + 0]), "v"(pv[mt * 4 + 1]));
      asm("v_cvt_pk_bf16_f32 %0, %1, %2" : "=v"(w1) : "v"(pv[mt * 4 + 2]), "v"(pv[mt * 4 + 3]));
      wq[nt][mt * 2 + 0] = w0;
      wq[nt][mt * 2 + 1] = w1;
    }
  }

  // ---- shuffle P words into PV A-fragments ----
  // target (mt2, ks, wj2): k-pair = ks*32 + g*8 + 2*wj2, q = mt2*16 + c
  // source lane (g_src = (g&1)*2 + (wj2>>1), c); word wq[mt2][mt_src*2 + (wj2&1)],
  // mt_src = 2ks + (g>>1)  -> two shfls (mt_src 2ks / 2ks+1) + select by g.
  bf16x8 pa[4][2];
#pragma unroll
  for (int mt2 = 0; mt2 < 4; ++mt2)
#pragma unroll
    for (int ks = 0; ks < 2; ++ks) {
      union { u32 u[4]; bf16x8 v; } cvt;
#pragma unroll
      for (int wj2 = 0; wj2 < 4; ++wj2) {
        int srcLane = c + 16 * (((g & 1) << 1) + (wj2 >> 1));
        u32 a0 = (u32)__shfl((int)wq[mt2][(2 * ks + 0) * 2 + (wj2 & 1)], srcLane);
        u32 a1 = (u32)__shfl((int)wq[mt2][(2 * ks + 1) * 2 + (wj2 & 1)], srcLane);
        cvt.u[wj2] = (g < 2) ? a0 : a1;
      }
      pa[mt2][ks] = cvt.v;
    }

  // ---- PV: O = P @ V via mfma(pa, vf); vf = V^T[d = ntd*16+c][k-chunk] ----
  f32x4 o[4][2];
  f32x4 z2 = {0.f, 0.f, 0.f, 0.f};
#pragma unroll
  for (int mt2 = 0; mt2 < 4; ++mt2)
#pragma unroll
    for (int ntd = 0; ntd < 2; ++ntd) o[mt2][ntd] = z2;
#pragma unroll
  for (int ks = 0; ks < 2; ++ks) {
    bf16x8 vf[2];
#pragma unroll
    for (int ntd = 0; ntd < 2; ++ntd)
      vf[ntd] = *(const bf16x8*)&Vt[(ntd * 16 + c) * 72 + ks * 32 + g * 8];
#pragma unroll
    for (int mt2 = 0; mt2 < 4; ++mt2)
#pragma unroll
      for (int ntd = 0; ntd < 2; ++ntd)
        o[mt2][ntd] = __builtin_amdgcn_mfma_f32_16x16x32_bf16(pa[mt2][ks], vf[ntd], o[mt2][ntd], 0, 0, 0);
  }

  // ---- epilogue: O row q = mt2*16+g*4+reg, col d = ntd*16+c ----
#pragma unroll
  for (int mt2 = 0; mt2 < 4; ++mt2)
#pragma unroll
    for (int r = 0; r < 4; ++r) {
      int q = mt2 * 16 + g * 4 + r;
      if (q < 49) {
        int row = Rows[q + 1];
        u16* op = aout + (size_t)row * 384 + h * 32 + c;
        op[0]  = f2b(o[mt2][0][r]);
        op[16] = f2b(o[mt2][1][r]);
      }
    }
}

// ---------------- launcher ----------------
extern "C" void kernel_launch(void* const* d_in, const int* in_sizes, int n_in,
                              void* d_out, int out_size, void* d_ws, size_t ws_size,
                              hipStream_t stream) {
  const float* x      = (const float*)d_in[0];
  const float* n1g    = (const float*)d_in[1];
  const float* n1b    = (const float*)d_in[2];
  const float* qkv_w  = (const float*)d_in[3];
  const float* qkv_b  = (const float*)d_in[4];
  const float* relb   = (const float*)d_in[5];
  const float* proj_w = (const float*)d_in[6];
  const float* proj_b = (const float*)d_in[7];
  const float* n2g    = (const float*)d_in[8];
  const float* n2b    = (const float*)d_in[9];
  const float* fc1_w  = (const float*)d_in[10];
  const float* fc1_b  = (const float*)d_in[11];
  const float* fc2_w  = (const float*)d_in[12];
  const float* fc2_b  = (const float*)d_in[13];
  float* out = (float*)d_out;
  char* ws = (char*)d_ws;

  // workspace layout (total ~312 MB); x1 lives in d_out
  u16* wqkv  = (u16*)(ws + 0);                       //  884,736 B (dead after qkv GEMM)
  float* biasf = (float*)(ws + 0);                   //  786,432 B (reuses wqkv region)
  u16* wproj = (u16*)(ws + 884736);                  //  294,912 B
  u16* wfc1  = (u16*)(ws + 1179648);                 // 1,179,648 B
  u16* wfc2  = (u16*)(ws + 2359296);                 // 1,179,648 B
  u16* qkvb  = (u16*)(ws + 3538944);                 // 231,284,736 B (dead after attention)
  u16* h2b   = (u16*)(ws + 3538944);                 // reuse: LN2 chunk out (38.5 MB)
  u16* gb    = (u16*)(ws + 3538944 + 41943040);      // reuse: fc1 chunk out (154.2 MB)
  u16* hbuf  = (u16*)(ws + 234823680);               // 77,094,912 B (h, then attn_out)
  float* parts = (float*)d_out;                      // CLS partials: dead-until-proj d_out

  cvt_bf16<<<dim3((442368 + 255) / 256), 256, 0, stream>>>(qkv_w, wqkv, 442368);
  cvt_bf16<<<dim3((147456 + 255) / 256), 256, 0, stream>>>(proj_w, wproj, 147456);
  cvt_bf16<<<dim3((589824 + 255) / 256), 256, 0, stream>>>(fc1_w, wfc1, 589824);
  cvt_bf16<<<dim3((589824 + 255) / 256), 256, 0, stream>>>(fc2_w, wfc2, 589824);

  ln384<<<kM, 64, 0, stream>>>(x, n1g, n1b, hbuf, kM);
  gemm_bt<0><<<dim3(9, 785), 256, 0, stream>>>(hbuf, wqkv, qkv_b, nullptr, qkvb, kM, 1152, 384);
  bias_pre<<<48, 256, 0, stream>>>(relb, biasf);     // into dead wqkv region
  cls_part<<<dim3(kB * kHeads, kNC), 256, 0, stream>>>(qkvb, parts);
  cls_reduce<<<kB * kHeads, 64, 0, stream>>>(parts, hbuf);
  win_attn2<<<kB * 64 * kHeads / 4, 256, 0, stream>>>(qkvb, biasf, hbuf);
  gemm_bt<1><<<dim3(3, 785), 256, 0, stream>>>(hbuf, wproj, proj_b, x, out, kM, 384, 384);

  for (int c = 0; c < 2; c++) {
    int r0 = c * 50192, nr = 50192;
    ln384<<<nr, 64, 0, stream>>>(out + (size_t)r0 * 384, n2g, n2b, h2b, nr);
    gemm_bt<2><<<dim3(12, 393), 256, 0, stream>>>(h2b, wfc1, fc1_b, nullptr, gb, nr, 1536, 384);
    gemm_bt<1><<<dim3(3, 393), 256, 0, stream>>>(gb, wfc2, fc2_b, out + (size_t)r0 * 384,
                                                 out + (size_t)r0 * 384, nr, 384, 1536);
  }
}

// Round 4
// 1000.072 us; speedup vs baseline: 1.2805x; 1.0154x over previous
//
#include <hip/hip_runtime.h>

#define DEVI __device__ __forceinline__

typedef __attribute__((ext_vector_type(8))) __bf16 bf16x8;
typedef __attribute__((ext_vector_type(4))) float f32x4;
typedef unsigned short u16;
typedef unsigned int u32;

static constexpr int kB = 32;
static constexpr int kL = 3137;           // 56*56+1
static constexpr int kM = kB * kL;        // 100384 rows total
static constexpr int kHeads = 12;
static constexpr float kScale = 0.17677669529663687f;  // 32^-0.5
static constexpr int kNC = 13;            // CLS key chunks of 256 (13*256 >= 3137)

DEVI u16 f2b(float f) {                   // f32 -> bf16 RNE
  u32 u = __float_as_uint(f);
  u32 r = (u + 0x7fffu + ((u >> 16) & 1u)) >> 16;
  return (u16)r;
}
DEVI float blo(u32 u) { return __uint_as_float(u << 16); }
DEVI float bhi(u32 u) { return __uint_as_float(u & 0xffff0000u); }
DEVI float b2f(u16 h) { return __uint_as_float(((u32)h) << 16); }

DEVI void async16(const void* g, void* l) {
  __builtin_amdgcn_global_load_lds((const __attribute__((address_space(1))) u32*)g,
                                   (__attribute__((address_space(3))) u32*)l, 16, 0, 0);
}

DEVI float wred_max(float v) {
#pragma unroll
  for (int o = 32; o; o >>= 1) v = fmaxf(v, __shfl_xor(v, o));
  return v;
}
DEVI float wred_sum(float v) {
#pragma unroll
  for (int o = 32; o; o >>= 1) v += __shfl_xor(v, o);
  return v;
}

// ---------------- weight f32 -> bf16 ----------------
__global__ void cvt_bf16(const float* __restrict__ in, u16* __restrict__ out, int n) {
  int i = blockIdx.x * 256 + threadIdx.x;
  if (i < n) out[i] = f2b(in[i]);
}

// ---------------- LayerNorm over 384, one wave per row, bf16 out ----------------
__global__ __launch_bounds__(64)
void ln384(const float* __restrict__ x, const float* __restrict__ g,
           const float* __restrict__ b, u16* __restrict__ out, int rows) {
  int row = blockIdx.x;
  if (row >= rows) return;
  const float* xr = x + (size_t)row * 384;
  int t = threadIdx.x;
  float v[6], s = 0.f, s2 = 0.f;
#pragma unroll
  for (int i = 0; i < 6; i++) {
    v[i] = xr[t + 64 * i];
    s += v[i];
    s2 += v[i] * v[i];
  }
  s = wred_sum(s);
  s2 = wred_sum(s2);
  float mean = s * (1.f / 384.f);
  float var = s2 * (1.f / 384.f) - mean * mean;
  float rinv = rsqrtf(var + 1e-5f);
  u16* orow = out + (size_t)row * 384;
#pragma unroll
  for (int i = 0; i < 6; i++) {
    int c = t + 64 * i;
    orow[c] = f2b((v[i] - mean) * rinv * g[c] + b[c]);
  }
}

DEVI float gelu_exact(float v) { return 0.5f * v * (1.f + erff(v * 0.70710678118654752f)); }

// ---------------- bf16 MFMA GEMM:  out = A(MxK) @ W(NxK)^T + bias [+res] ----------------
// 128x128 tile, BK=32, 4 waves (2x2), 4x4 frags of 16x16x32 per wave.
// Triple-buffered LDS + counted vmcnt(4) across raw barriers (T3/T4 minimum),
// T2 both-sides swizzle (pre-swizzled global source, swizzled ds_read),
// T1 bijective XCD grid swizzle, T5 setprio around MFMA cluster.
// EPI: 0 = bias -> bf16 ; 1 = bias + res -> f32 ; 2 = bias + gelu -> bf16
template <int EPI>
__global__ __launch_bounds__(256)
void gemm_bt(const u16* __restrict__ A, const u16* __restrict__ W,
             const float* __restrict__ bias, const float* __restrict__ res,
             void* __restrict__ outp, int M, int N, int K, int NX) {
  // ---- T1: bijective XCD swizzle (m204) on flattened 1D grid ----
  {
  }
  const int nwg = gridDim.x;
  const int orig = blockIdx.x;
  const int xcd = orig & 7, rest = orig >> 3;
  const int q8 = nwg >> 3, r8 = nwg & 7;
  const int id = ((xcd < r8) ? xcd * (q8 + 1) : r8 * (q8 + 1) + (xcd - r8) * q8) + rest;
  const int col0 = (id % NX) * 128, row0 = (id / NX) * 128;

  const int tid = threadIdx.x, lane = tid & 63, wv = tid >> 6;
  __shared__ __align__(16) u16 As[3][128 * 32];
  __shared__ __align__(16) u16 Bs[3][128 * 32];
  f32x4 acc[4][4];
  f32x4 zero = {0.f, 0.f, 0.f, 0.f};
#pragma unroll
  for (int m = 0; m < 4; m++)
#pragma unroll
    for (int n = 0; n < 4; n++) acc[m][n] = zero;
  const int wm = wv >> 1, wn = wv & 1;
  const int c = lane & 15, g = lane >> 4;
  const int NT = K >> 5;

  // staging: LDS stays linear (wave-uniform base + lane*16); global source is
  // pre-permuted so that the swizzled read below finds (row, g) at
  // u16 idx = row*32 + ((g ^ ((row>>1)&3))<<3). Within-line lane permutation
  // only -> still fully coalesced.
  auto stage = [&](int kt, int bfi) {
#pragma unroll
    for (int s = 0; s < 2; s++) {
      int ch = wv * 2 + s;                       // 8 chunks of 16 rows x 64B
      int r = ch * 16 + (lane >> 2);
      int gnat = (lane & 3) ^ ((lane >> 3) & 3); // source pre-swizzle
      int kk = kt * 32 + gnat * 8;
      const u16* gp = A + (size_t)min(row0 + r, M - 1) * K + kk;
      async16(gp, &As[bfi][ch * 512]);
      const u16* gq = W + (size_t)min(col0 + r, N - 1) * K + kk;
      async16(gq, &Bs[bfi][ch * 512]);
    }
  };

  stage(0, 0);                                   // 4 loads
  stage(1, 1);                                   // 8 outstanding
  int cur = 0;
  for (int kt = 0; kt < NT; ++kt) {
    if (kt + 1 < NT) asm volatile("s_waitcnt vmcnt(4)" ::: "memory");
    else             asm volatile("s_waitcnt vmcnt(0)" ::: "memory");
    __builtin_amdgcn_s_barrier();                // all waves' tile-kt loads landed
    if (kt + 2 < NT) {
      int nb = cur + 2; if (nb >= 3) nb -= 3;
      stage(kt + 2, nb);                         // overwrites tile kt-1's buffer (safe)
    }
    bf16x8 af[4], bw[4];
#pragma unroll
    for (int m = 0; m < 4; m++) {
      int row = wm * 64 + m * 16 + c;
      af[m] = *(const bf16x8*)&As[cur][row * 32 + ((g ^ ((row >> 1) & 3)) << 3)];
    }
#pragma unroll
    for (int n = 0; n < 4; n++) {
      int row = wn * 64 + n * 16 + c;
      bw[n] = *(const bf16x8*)&Bs[cur][row * 32 + ((g ^ ((row >> 1) & 3)) << 3)];
    }
    __builtin_amdgcn_s_setprio(1);
#pragma unroll
    for (int m = 0; m < 4; m++)
#pragma unroll
      for (int n = 0; n < 4; n++)
        acc[m][n] = __builtin_amdgcn_mfma_f32_16x16x32_bf16(af[m], bw[n], acc[m][n], 0, 0, 0);
    __builtin_amdgcn_s_setprio(0);
    cur = cur + 1; if (cur >= 3) cur -= 3;
  }

  int cc[4];
  float bv[4];
#pragma unroll
  for (int n = 0; n < 4; n++) {
    cc[n] = col0 + wn * 64 + n * 16 + c;
    bv[n] = bias[cc[n]];
  }
#pragma unroll
  for (int m = 0; m < 4; m++) {
    int rb = row0 + wm * 64 + m * 16 + (g << 2);
#pragma unroll
    for (int j = 0; j < 4; j++) {
      int r = rb + j;
      if (r < M) {
#pragma unroll
        for (int n = 0; n < 4; n++) {
          float vv = acc[m][n][j] + bv[n];
          size_t off = (size_t)r * N + cc[n];
          if constexpr (EPI == 0) {
            ((u16*)outp)[off] = f2b(vv);
          } else if constexpr (EPI == 1) {
            ((float*)outp)[off] = vv + res[off];
          } else {
            ((u16*)outp)[off] = f2b(gelu_exact(vv));
          }
        }
      }
    }
  }
}

// ---------------- CLS attention, flash-decode phase 1 ----------------
// grid (b*12+h, chunk); 256 threads; one key-token per thread.
// Writes partials [bh][chunk]: {m, expsum, o[32]} (34 floats).
__global__ __launch_bounds__(256)
void cls_part(const u16* __restrict__ qkv, float* __restrict__ parts) {
  int bh = blockIdx.x;
  int chunk = blockIdx.y;
  int b = bh / kHeads, h = bh % kHeads;
  __shared__ float qs[32];
  __shared__ float ps[256];
  __shared__ float red[8];
  __shared__ float part[8][32];
  int tid = threadIdx.x, lane = tid & 63, wv = tid >> 6;
  size_t rb = (size_t)b * kL;
  if (tid < 32) qs[tid] = b2f(qkv[rb * 1152 + h * 32 + tid]) * kScale;
  __syncthreads();
  int t0 = chunk * 256;
  int nTok = min(256, kL - t0);
  float s = -1e30f;
  if (tid < nTok) {
    const u16* kp = qkv + (rb + t0 + tid) * 1152 + 384 + h * 32;
    s = 0.f;
#pragma unroll
    for (int g4 = 0; g4 < 4; g4++) {
      uint4 u = *(const uint4*)(kp + g4 * 8);
      s += qs[g4*8+0]*blo(u.x) + qs[g4*8+1]*bhi(u.x)
         + qs[g4*8+2]*blo(u.y) + qs[g4*8+3]*bhi(u.y)
         + qs[g4*8+4]*blo(u.z) + qs[g4*8+5]*bhi(u.z)
         + qs[g4*8+6]*blo(u.w) + qs[g4*8+7]*bhi(u.w);
    }
  }
  float m = wred_max(s);
  if (lane == 0) red[wv] = m;
  __syncthreads();
  float gm = fmaxf(fmaxf(red[0], red[1]), fmaxf(red[2], red[3]));
  float p = (tid < nTok) ? __expf(s - gm) : 0.f;
  ps[tid] = p;
  float ls = wred_sum(p);
  if (lane == 0) red[4 + wv] = ls;
  __syncthreads();
  float tot = red[4] + red[5] + red[6] + red[7];
  // weighted V partial
  int d = tid & 31, g = tid >> 5;
  float a = 0.f;
  for (int t = g; t < nTok; t += 8)
    a += ps[t] * b2f(qkv[(rb + t0 + t) * 1152 + 768 + h * 32 + d]);
  part[g][d] = a;
  __syncthreads();
  if (tid < 32) {
    float o = 0.f;
#pragma unroll
    for (int g2 = 0; g2 < 8; g2++) o += part[g2][tid];
    float* pp = parts + ((size_t)bh * kNC + chunk) * 34;
    pp[2 + tid] = o;
    if (tid == 0) { pp[0] = gm; pp[1] = tot; }
  }
}

// ---------------- CLS attention, phase 2: LSE-merge 13 chunks ----------------
__global__ __launch_bounds__(64)
void cls_reduce(const float* __restrict__ parts, u16* __restrict__ aout) {
  int bh = blockIdx.x;
  int b = bh / kHeads, h = bh % kHeads;
  int tid = threadIdx.x;
  __shared__ float sm[kNC], ss[kNC];
  if (tid < kNC) {
    sm[tid] = parts[((size_t)bh * kNC + tid) * 34];
    ss[tid] = parts[((size_t)bh * kNC + tid) * 34 + 1];
  }
  __syncthreads();
  float M = -1e30f;
#pragma unroll
  for (int c = 0; c < kNC; c++) M = fmaxf(M, sm[c]);
  float W = 0.f;
#pragma unroll
  for (int c = 0; c < kNC; c++) W += ss[c] * __expf(sm[c] - M);
  if (tid < 32) {
    float o = 0.f;
#pragma unroll
    for (int c = 0; c < kNC; c++)
      o += parts[((size_t)bh * kNC + c) * 34 + 2 + tid] * __expf(sm[c] - M);
    aout[(size_t)b * kL * 384 + h * 32 + tid] = f2b(o / W);
  }
}

// ---------------- precompute bias_full[class][head][k][q] (64x64 per pair) ----------------
// k=0: CLS key (no bias/mask). k in [1,50): rel bias + region mask. k>=50: -1e9 (pad kill).
__global__ __launch_bounds__(256)
void bias_pre(const float* __restrict__ relb, float* __restrict__ bf) {
  int blk = blockIdx.x;           // cls*12 + h
  int cls = blk / 12, h = blk % 12;
  int clsH = (cls >> 1) & 1, clsW = cls & 1;
  for (int idx = threadIdx.x; idx < 4096; idx += 256) {
    int k = idx >> 6, q = idx & 63;
    float v = 0.f;
    if (k >= 50) {
      v = -1e9f;
    } else if (k >= 1 && q < 49) {
      int kt = k - 1, ki = kt / 7, kj = kt % 7;
      int qi = q / 7, qj = q % 7;
      v = relb[((qi - ki + 6) * 13 + (qj - kj + 6)) * 12 + h];
      int rq = (clsH ? (qi < 4 ? 1 : 2) : 0) * 3 + (clsW ? (qj < 4 ? 1 : 2) : 0);
      int rk = (clsH ? (ki < 4 ? 1 : 2) : 0) * 3 + (clsW ? (kj < 4 ? 1 : 2) : 0);
      if (rq != rk) v -= 100.f;
    }
    bf[(size_t)blk * 4096 + idx] = v;
  }
}

// ---------------- shifted-window attention, MFMA version ----------------
// 1 wave per (window, head), 4 waves/block. Swapped QK^T (S^T = mfma(K,Q)),
// in-register softmax per q-column, cvt_pk + shfl to PV A-fragments, MFMA PV
// against LDS-transposed V.
__global__ __launch_bounds__(256)
void win_attn2(const u16* __restrict__ qkv, const float* __restrict__ biasf,
               u16* __restrict__ aout) {
  const int tid = threadIdx.x, lane = tid & 63, wv = tid >> 6;
  const int gid = blockIdx.x * 4 + wv;
  const int h = gid % 12;
  const int wr = gid / 12;        // 0..2047
  const int win = wr & 63, b = wr >> 6;
  const int wi = win >> 3, wj = win & 7;
  const int cls = ((wi == 7) ? 2 : 0) + ((wj == 7) ? 1 : 0);
  const int c = lane & 15, g = lane >> 4;

  // per-wave LDS slices; strides chosen for uniform bank-group spread on b128
  __shared__ __align__(16) u16 KS[4][64 * 40];   // K row-major, row stride 40 u16 (80B)
  __shared__ __align__(16) u16 VT[4][32 * 72];   // V transposed [d][tok], stride 72 u16
  __shared__ int RW[4][52];
  u16* Ks = KS[wv];
  u16* Vt = VT[wv];
  int* Rows = RW[wv];

  // ---- staging: tasks (tok 0..63) x (half 0..1), 2 iters ----
#pragma unroll
  for (int it = 0; it < 2; ++it) {
    int idx = it * 64 + lane;
    int tok = idx >> 1, half = idx & 1;
    if (tok < 50) {
      int row;
      if (tok == 0) {
        row = b * kL;                                  // CLS
      } else {
        int n = tok - 1;
        int i = n / 7, j = n % 7;
        int r = wi * 7 + i, c2 = wj * 7 + j;           // rolled-canvas coords
        int orr = r + 3; if (orr >= 56) orr -= 56;     // original coords
        int occ = c2 + 3; if (occ >= 56) occ -= 56;
        row = b * kL + 1 + orr * 56 + occ;
      }
      if (half == 0) Rows[tok] = row;
      const u16* base = qkv + (size_t)row * 1152 + h * 32 + half * 16;
      uint4 k0 = *(const uint4*)(base + 384);
      uint4 k1 = *(const uint4*)(base + 384 + 8);
      *(uint4*)&Ks[tok * 40 + half * 16] = k0;
      *(uint4*)&Ks[tok * 40 + half * 16 + 8] = k1;
      uint4 v0 = *(const uint4*)(base + 768);
      uint4 v1 = *(const uint4*)(base + 768 + 8);
      u32 vw[8] = {v0.x, v0.y, v0.z, v0.w, v1.x, v1.y, v1.z, v1.w};
#pragma unroll
      for (int m = 0; m < 8; ++m) {                    // dims d = half*16 + 2m{,+1}
        Vt[(half * 16 + m * 2 + 0) * 72 + tok] = (u16)(vw[m] & 0xffffu);
        Vt[(half * 16 + m * 2 + 1) * 72 + tok] = (u16)(vw[m] >> 16);
      }
    } else {                                           // pad rows/cols -> zero
      uint4 z = {0u, 0u, 0u, 0u};
      *(uint4*)&Ks[tok * 40 + half * 16] = z;
      *(uint4*)&Ks[tok * 40 + half * 16 + 8] = z;
#pragma unroll
      for (int m = 0; m < 16; ++m) Vt[(half * 16 + m) * 72 + tok] = 0;
    }
  }
  __syncthreads();

  // ---- Q fragments (B-operand): lane holds Q[q = nt*16+c][d = g*8 .. +7] ----
  bf16x8 qf[4];
#pragma unroll
  for (int nt = 0; nt < 4; ++nt) {
    int q = nt * 16 + c;
    if (q > 48) q = 48;                                // clamp pad cols (discarded)
    const u16* qp = qkv + (size_t)Rows[q + 1] * 1152 + h * 32 + g * 8;
    qf[nt] = *(const bf16x8*)qp;
  }

  // ---- QK^T: S^T tiles. s[mt][nt]: row k=mt*16+g*4+reg, col q=nt*16+c ----
  f32x4 s[4][4];
  {
    f32x4 z = {0.f, 0.f, 0.f, 0.f};
    bf16x8 kf[4];
#pragma unroll
    for (int mt = 0; mt < 4; ++mt)
      kf[mt] = *(const bf16x8*)&Ks[(mt * 16 + c) * 40 + g * 8];
#pragma unroll
    for (int mt = 0; mt < 4; ++mt)
#pragma unroll
      for (int nt = 0; nt < 4; ++nt)
        s[mt][nt] = __builtin_amdgcn_mfma_f32_16x16x32_bf16(kf[mt], qf[nt], z, 0, 0, 0);
  }

  // ---- scale + bias + mask, softmax per q-column, normalize, pack to bf16 ----
  const float* bp = biasf + (size_t)(cls * 12 + h) * 4096;
  u32 wq[4][8];                                        // [nt][mt*2 + wbit]
#pragma unroll
  for (int nt = 0; nt < 4; ++nt) {
    float pv[16];
#pragma unroll
    for (int mt = 0; mt < 4; ++mt)
#pragma unroll
      for (int r = 0; r < 4; ++r)
        pv[mt * 4 + r] = s[mt][nt][r] * kScale + bp[(mt * 16 + g * 4 + r) * 64 + nt * 16 + c];
    float mx = pv[0];
#pragma unroll
    for (int i2 = 1; i2 < 16; ++i2) mx = fmaxf(mx, pv[i2]);
    mx = fmaxf(mx, __shfl_xor(mx, 16));
    mx = fmaxf(mx, __shfl_xor(mx, 32));
    float sum = 0.f;
#pragma unroll
    for (int i2 = 0; i2 < 16; ++i2) { pv[i2] = __expf(pv[i2] - mx); sum += pv[i2]; }
    sum += __shfl_xor(sum, 16);
    sum += __shfl_xor(sum, 32);
    float rs = 1.f / sum;
#pragma unroll
    for (int i2 = 0; i2 < 16; ++i2) pv[i2] *= rs;
#pragma unroll
    for (int mt = 0; mt < 4; ++mt) {
      u32 w0, w1;
      asm("v_cvt_pk_bf16_f32 %0, %1, %2" : "=v"(w0) : "v"(pv[mt * 4 + 0]), "v"(pv[mt * 4 + 1]));
      asm("v_cvt_pk_bf16_f32 %0, %1, %2" : "=v"(w1) : "v"(pv[mt * 4 + 2]), "v"(pv[mt * 4 + 3]));
      wq[nt][mt * 2 + 0] = w0;
      wq[nt][mt * 2 + 1] = w1;
    }
  }

  // ---- shuffle P words into PV A-fragments ----
  // target (mt2, ks, wj2): k-pair = ks*32 + g*8 + 2*wj2, q = mt2*16 + c
  // source lane (g_src = (g&1)*2 + (wj2>>1), c); word wq[mt2][mt_src*2 + (wj2&1)],
  // mt_src = 2ks + (g>>1)  -> two shfls (mt_src 2ks / 2ks+1) + select by g.
  bf16x8 pa[4][2];
#pragma unroll
  for (int mt2 = 0; mt2 < 4; ++mt2)
#pragma unroll
    for (int ks = 0; ks < 2; ++ks) {
      union { u32 u[4]; bf16x8 v; } cvt;
#pragma unroll
      for (int wj2 = 0; wj2 < 4; ++wj2) {
        int srcLane = c + 16 * (((g & 1) << 1) + (wj2 >> 1));
        u32 a0 = (u32)__shfl((int)wq[mt2][(2 * ks + 0) * 2 + (wj2 & 1)], srcLane);
        u32 a1 = (u32)__shfl((int)wq[mt2][(2 * ks + 1) * 2 + (wj2 & 1)], srcLane);
        cvt.u[wj2] = (g < 2) ? a0 : a1;
      }
      pa[mt2][ks] = cvt.v;
    }

  // ---- PV: O = P @ V via mfma(pa, vf); vf = V^T[d = ntd*16+c][k-chunk] ----
  f32x4 o[4][2];
  f32x4 z2 = {0.f, 0.f, 0.f, 0.f};
#pragma unroll
  for (int mt2 = 0; mt2 < 4; ++mt2)
#pragma unroll
    for (int ntd = 0; ntd < 2; ++ntd) o[mt2][ntd] = z2;
#pragma unroll
  for (int ks = 0; ks < 2; ++ks) {
    bf16x8 vf[2];
#pragma unroll
    for (int ntd = 0; ntd < 2; ++ntd)
      vf[ntd] = *(const bf16x8*)&Vt[(ntd * 16 + c) * 72 + ks * 32 + g * 8];
#pragma unroll
    for (int mt2 = 0; mt2 < 4; ++mt2)
#pragma unroll
      for (int ntd = 0; ntd < 2; ++ntd)
        o[mt2][ntd] = __builtin_amdgcn_mfma_f32_16x16x32_bf16(pa[mt2][ks], vf[ntd], o[mt2][ntd], 0, 0, 0);
  }

  // ---- epilogue: O row q = mt2*16+g*4+reg, col d = ntd*16+c ----
#pragma unroll
  for (int mt2 = 0; mt2 < 4; ++mt2)
#pragma unroll
    for (int r = 0; r < 4; ++r) {
      int q = mt2 * 16 + g * 4 + r;
      if (q < 49) {
        int row = Rows[q + 1];
        u16* op = aout + (size_t)row * 384 + h * 32 + c;
        op[0]  = f2b(o[mt2][0][r]);
        op[16] = f2b(o[mt2][1][r]);
      }
    }
}

// ---------------- launcher ----------------
extern "C" void kernel_launch(void* const* d_in, const int* in_sizes, int n_in,
                              void* d_out, int out_size, void* d_ws, size_t ws_size,
                              hipStream_t stream) {
  const float* x      = (const float*)d_in[0];
  const float* n1g    = (const float*)d_in[1];
  const float* n1b    = (const float*)d_in[2];
  const float* qkv_w  = (const float*)d_in[3];
  const float* qkv_b  = (const float*)d_in[4];
  const float* relb   = (const float*)d_in[5];
  const float* proj_w = (const float*)d_in[6];
  const float* proj_b = (const float*)d_in[7];
  const float* n2g    = (const float*)d_in[8];
  const float* n2b    = (const float*)d_in[9];
  const float* fc1_w  = (const float*)d_in[10];
  const float* fc1_b  = (const float*)d_in[11];
  const float* fc2_w  = (const float*)d_in[12];
  const float* fc2_b  = (const float*)d_in[13];
  float* out = (float*)d_out;
  char* ws = (char*)d_ws;

  // workspace layout (total ~312 MB); x1 lives in d_out
  u16* wqkv  = (u16*)(ws + 0);                       //  884,736 B (dead after qkv GEMM)
  float* biasf = (float*)(ws + 0);                   //  786,432 B (reuses wqkv region)
  u16* wproj = (u16*)(ws + 884736);                  //  294,912 B
  u16* wfc1  = (u16*)(ws + 1179648);                 // 1,179,648 B
  u16* wfc2  = (u16*)(ws + 2359296);                 // 1,179,648 B
  u16* qkvb  = (u16*)(ws + 3538944);                 // 231,284,736 B (dead after attention)
  u16* h2b   = (u16*)(ws + 3538944);                 // reuse: LN2 chunk out (38.5 MB)
  u16* gb    = (u16*)(ws + 3538944 + 41943040);      // reuse: fc1 chunk out (154.2 MB)
  u16* hbuf  = (u16*)(ws + 234823680);               // 77,094,912 B (h, then attn_out)
  float* parts = (float*)d_out;                      // CLS partials: dead-until-proj d_out

  cvt_bf16<<<dim3((442368 + 255) / 256), 256, 0, stream>>>(qkv_w, wqkv, 442368);
  cvt_bf16<<<dim3((147456 + 255) / 256), 256, 0, stream>>>(proj_w, wproj, 147456);
  cvt_bf16<<<dim3((589824 + 255) / 256), 256, 0, stream>>>(fc1_w, wfc1, 589824);
  cvt_bf16<<<dim3((589824 + 255) / 256), 256, 0, stream>>>(fc2_w, wfc2, 589824);

  ln384<<<kM, 64, 0, stream>>>(x, n1g, n1b, hbuf, kM);
  gemm_bt<0><<<9 * 785, 256, 0, stream>>>(hbuf, wqkv, qkv_b, nullptr, qkvb, kM, 1152, 384, 9);
  bias_pre<<<48, 256, 0, stream>>>(relb, biasf);     // into dead wqkv region
  cls_part<<<dim3(kB * kHeads, kNC), 256, 0, stream>>>(qkvb, parts);
  cls_reduce<<<kB * kHeads, 64, 0, stream>>>(parts, hbuf);
  win_attn2<<<kB * 64 * kHeads / 4, 256, 0, stream>>>(qkvb, biasf, hbuf);
  gemm_bt<1><<<3 * 785, 256, 0, stream>>>(hbuf, wproj, proj_b, x, out, kM, 384, 384, 3);

  for (int c = 0; c < 2; c++) {
    int r0 = c * 50192, nr = 50192;
    ln384<<<nr, 64, 0, stream>>>(out + (size_t)r0 * 384, n2g, n2b, h2b, nr);
    gemm_bt<2><<<12 * 393, 256, 0, stream>>>(h2b, wfc1, fc1_b, nullptr, gb, nr, 1536, 384, 12);
    gemm_bt<1><<<3 * 393, 256, 0, stream>>>(gb, wfc2, fc2_b, out + (size_t)r0 * 384,
                                            out + (size_t)r0 * 384, nr, 384, 1536, 3);
  }
}